// Round 4
// baseline (294.500 us; speedup 1.0000x reference)
//
#include <hip/hip_runtime.h>

typedef _Float16 f16;
typedef _Float16 f16x8 __attribute__((ext_vector_type(8)));
typedef _Float16 f16x4 __attribute__((ext_vector_type(4)));
typedef float f32x4 __attribute__((ext_vector_type(4)));
typedef float f32x16 __attribute__((ext_vector_type(16)));

#define MFMA16(A, B, C) __builtin_amdgcn_mfma_f32_16x16x32_f16((A), (B), (C), 0, 0, 0)
#define MFMA32(A, B, C) __builtin_amdgcn_mfma_f32_32x32x16_f16((A), (B), (C), 0, 0, 0)

// async global->LDS, 16B per lane, dest = wave-uniform base + lane*16
__device__ __forceinline__ void async16(void* lds, const void* gp) {
    __builtin_amdgcn_global_load_lds(
        (__attribute__((address_space(1))) void*)(gp),
        (__attribute__((address_space(3))) void*)(lds), 16, 0, 0);
}

// ---------------- fp32 -> fp16 cast (vectorized) ----------------
__global__ __launch_bounds__(256) void k_convert(const float* __restrict__ in,
                                                 f16* __restrict__ out, int n) {
    int i = (blockIdx.x * 256 + threadIdx.x) * 4;
    if (i + 3 < n) {
        float4 v = *(const float4*)(in + i);
        f16x4 o = {(f16)v.x, (f16)v.y, (f16)v.z, (f16)v.w};
        *(f16x4*)(out + i) = o;
    }
}

// ---------------- transpose + cast all four 1024x1024 weights in one launch ----------------
__global__ __launch_bounds__(256) void k_transpose_w4(const float* __restrict__ Wq,
                                                      const float* __restrict__ Wk,
                                                      const float* __restrict__ Wv,
                                                      const float* __restrict__ Wr,
                                                      f16* __restrict__ Wqkvt,
                                                      f16* __restrict__ Wrt) {
    __shared__ float tile[32][33];
    int z = blockIdx.z;
    const float* W = (z == 0) ? Wq : (z == 1) ? Wk : (z == 2) ? Wv : Wr;
    f16* Wt = (z == 3) ? Wrt : Wqkvt + z * 1048576;
    int c0 = blockIdx.x * 32, r0 = blockIdx.y * 32;
    int tx = threadIdx.x, ty = threadIdx.y;  // 32 x 8
#pragma unroll
    for (int j = 0; j < 32; j += 8)
        tile[ty + j][tx] = W[(r0 + ty + j) * 1024 + c0 + tx];
    __syncthreads();
#pragma unroll
    for (int j = 0; j < 32; j += 8)
        Wt[(c0 + ty + j) * 1024 + r0 + tx] = (f16)tile[tx][ty + j];
}

// ---------------- transpose V slice of QKV into Vt[bh][d][s] ----------------
__global__ __launch_bounds__(256) void k_transpose_v(const f16* __restrict__ QKV,
                                                     f16* __restrict__ Vt) {
    __shared__ f16 tile[32][33];
    int s0 = blockIdx.x * 32;
    int d0 = blockIdx.y * 32;
    int bh = blockIdx.z;
    int b = bh >> 4, h = bh & 15;
    int tx = threadIdx.x, ty = threadIdx.y;  // 32 x 8
#pragma unroll
    for (int j = 0; j < 32; j += 8)
        tile[ty + j][tx] = QKV[(b * 2048 + s0 + ty + j) * 3072 + 2048 + h * 64 + d0 + tx];
    __syncthreads();
#pragma unroll
    for (int j = 0; j < 32; j += 8)
        Vt[(bh * 64 + d0 + ty + j) * 2048 + s0 + tx] = tile[tx][ty + j];
}

// ---------------- GEMM: C[M][N] = A[M][K] * Bt[N][K]^T, 32x32x16 MFMA ----------------
// 128x128 block tile, BK=32, 256 threads; 4 waves in 2x2, each wave 64x64 via 2x2 of 32x32.
// Unpadded LDS with 16B-chunk swizzle slot = c ^ ((row>>1)&3); async16 staging.
template <bool OUT_F16>
__global__ __launch_bounds__(256, 4) void k_gemm_bt(const f16* __restrict__ A,
                                                    const f16* __restrict__ Bt,
                                                    void* __restrict__ Cv,
                                                    int M, int N, int K) {
    __shared__ f16 As[128][32];
    __shared__ f16 Bs[128][32];
    int t = threadIdx.x;
    int lane = t & 63, w = t >> 6;
    int wm = (w >> 1) * 64, wn = (w & 1) * 64;
    int m0 = blockIdx.y * 128, n0 = blockIdx.x * 128;
    int ln = lane & 31, kh = lane >> 5;  // 32x32 fragment coords
    int sw = (ln >> 1) & 3;              // read-side swizzle key

    // async staging map: LDS position lin -> (row, slot); fetch global chunk c = slot ^ key(row)
    int lin0 = w * 128 + lane, lin1 = lin0 + 64;
    int r0 = lin0 >> 2, c0 = (lin0 & 3) ^ ((r0 >> 1) & 3);
    int r1 = lin1 >> 2, c1 = (lin1 & 3) ^ ((r1 >> 1) & 3);
    const f16* gA0 = A + (size_t)(m0 + r0) * K + c0 * 8;
    const f16* gA1 = A + (size_t)(m0 + r1) * K + c1 * 8;
    const f16* gB0 = Bt + (size_t)(n0 + r0) * K + c0 * 8;
    const f16* gB1 = Bt + (size_t)(n0 + r1) * K + c1 * 8;
    f16* lA0 = &As[0][0] + w * 1024;
    f16* lB0 = &Bs[0][0] + w * 1024;

    f32x16 acc[2][2] = {};

    for (int k0 = 0; k0 < K; k0 += 32) {
        __syncthreads();
        async16(lA0, gA0 + k0);
        async16(lA0 + 512, gA1 + k0);
        async16(lB0, gB0 + k0);
        async16(lB0 + 512, gB1 + k0);
        __syncthreads();
#pragma unroll
        for (int kd = 0; kd < 2; kd++) {
            int c = kd * 2 + kh;
            f16x8 af[2], bf[2];
#pragma unroll
            for (int mt = 0; mt < 2; mt++)
                af[mt] = *(const f16x8*)&As[wm + mt * 32 + ln][(c ^ sw) * 8];
#pragma unroll
            for (int nt = 0; nt < 2; nt++)
                bf[nt] = *(const f16x8*)&Bs[wn + nt * 32 + ln][(c ^ sw) * 8];
#pragma unroll
            for (int mt = 0; mt < 2; mt++)
#pragma unroll
                for (int nt = 0; nt < 2; nt++)
                    acc[mt][nt] = MFMA32(af[mt], bf[nt], acc[mt][nt]);
        }
    }

    // C/D map (32x32): col = lane&31, row = (r&3) + 8*(r>>2) + 4*(lane>>5)
#pragma unroll
    for (int mt = 0; mt < 2; mt++)
#pragma unroll
        for (int nt = 0; nt < 2; nt++)
#pragma unroll
            for (int r = 0; r < 16; r++) {
                int row = m0 + wm + mt * 32 + (r & 3) + 8 * (r >> 2) + 4 * kh;
                int col = n0 + wn + nt * 32 + ln;
                float v = acc[mt][nt][r];
                if (OUT_F16)
                    ((f16*)Cv)[(size_t)row * N + col] = (f16)v;
                else
                    ((float*)Cv)[(size_t)row * N + col] = v;
            }
}

// ---------------- flash attention v4 ----------------
// One q-tile per block: grid (64 bh, 16 qt reversed) = 1024 blocks = 4 blocks/CU.
// Register-prefetch staging; fixed-max softmax; MFMA ones-trick row sums.
__global__ __launch_bounds__(256, 4) void k_attn(const f16* __restrict__ QKV,
                                                 const f16* __restrict__ Vt,
                                                 f16* __restrict__ Ob) {
    __shared__ f16 Ks[64][72];
    __shared__ f16 Vs[64][72];   // V^T tile: [d][k]
    __shared__ f16 Ps[128][72];  // P in [q][k], wave-private rows
    int bh = blockIdx.x;
    int qt = 15 - (int)blockIdx.y;  // heavy q-tiles dispatch first
    int b = bh >> 4, h = bh & 15;
    int q0 = qt * 128;
    int t = threadIdx.x, lane = t & 63, wq = t >> 6;
    int ln = lane & 15, g = lane >> 4, g8 = g * 8, rg = g * 4;

    // staging coords: two K chunks + two V chunks per thread per tile
    int c0 = t, c1 = t + 256;
    int kr0 = c0 >> 3, kc0 = (c0 & 7) * 8;
    int kr1 = c1 >> 3, kc1 = (c1 & 7) * 8;
    const f16* Kbase = QKV + (size_t)b * 2048 * 3072 + 1024 + h * 64;
    const f16* Vbase = Vt + (size_t)bh * 64 * 2048;

    const float C_SCL = 0.18033688f;   // 0.125 * log2(e)
    const float C_MSK = -72.134752f;   // -50 * log2(e)
    f16x8 ones;
#pragma unroll
    for (int j = 0; j < 8; j++) ones[j] = (f16)1.f;

    // Q fragments (B-operand of S^T = K·Q^T); live in registers for the whole block
    f16x8 bq[2][2];
#pragma unroll
    for (int nt = 0; nt < 2; nt++)
#pragma unroll
        for (int kd = 0; kd < 2; kd++)
            bq[nt][kd] = *(const f16x8*)(QKV +
                (size_t)(b * 2048 + q0 + wq * 32 + nt * 16 + ln) * 3072 +
                h * 64 + kd * 32 + g8);

    // initial prefetch: tile 0
    int4 rk0 = *(const int4*)(Kbase + (size_t)kr0 * 3072 + kc0);
    int4 rk1 = *(const int4*)(Kbase + (size_t)kr1 * 3072 + kc1);
    int4 rv0 = *(const int4*)(Vbase + (size_t)kr0 * 2048 + kc0);
    int4 rv1 = *(const int4*)(Vbase + (size_t)kr1 * 2048 + kc1);

    f32x4 oacc[2][4] = {};
    f32x4 osum[2] = {};
    int nk = q0 / 64 + 2;  // causal tile skip (skipped tiles contribute ~e^-50)

    for (int kt = 0; kt < nk; kt++) {
        int k0 = kt * 64;
        __syncthreads();  // all waves done reading LDS from previous tile
        *(int4*)&Ks[kr0][kc0] = rk0;
        *(int4*)&Ks[kr1][kc1] = rk1;
        *(int4*)&Vs[kr0][kc0] = rv0;
        *(int4*)&Vs[kr1][kc1] = rv1;
        if (kt + 1 < nk) {  // prefetch next tile
            int kn = k0 + 64;
            rk0 = *(const int4*)(Kbase + (size_t)(kn + kr0) * 3072 + kc0);
            rk1 = *(const int4*)(Kbase + (size_t)(kn + kr1) * 3072 + kc1);
            rv0 = *(const int4*)(Vbase + (size_t)kr0 * 2048 + kn + kc0);
            rv1 = *(const int4*)(Vbase + (size_t)kr1 * 2048 + kn + kc1);
        }
        __syncthreads();

        // tile fully above this wave's diagonal -> contributes ~e^-50 ~ 0
        if (k0 > q0 + wq * 32 + 31) continue;  // wave-uniform; barriers outside

        // S^T tile: D[m=k][n=q]
        f32x4 sacc[4][2] = {};
#pragma unroll
        for (int kd = 0; kd < 2; kd++) {
            f16x8 ak[4];
#pragma unroll
            for (int mt = 0; mt < 4; mt++)
                ak[mt] = *(const f16x8*)&Ks[mt * 16 + ln][kd * 32 + g8];
#pragma unroll
            for (int mt = 0; mt < 4; mt++)
#pragma unroll
                for (int nt = 0; nt < 2; nt++)
                    sacc[mt][nt] = MFMA16(ak[mt], bq[nt][kd], sacc[mt][nt]);
        }

        // softmax numerator (fixed max 0): lane has q=..+ln, k=..+rg+r (4 consecutive)
        bool needs_mask = (k0 + 63 > q0 + wq * 32);
#pragma unroll
        for (int nt = 0; nt < 2; nt++) {
            int q = q0 + wq * 32 + nt * 16 + ln;
#pragma unroll
            for (int mt = 0; mt < 4; mt++) {
                f16x4 pk;
#pragma unroll
                for (int r = 0; r < 4; r++) {
                    float e;
                    if (needs_mask) {
                        int kk = k0 + mt * 16 + rg + r;
                        e = __builtin_amdgcn_exp2f(
                            fmaf(sacc[mt][nt][r], C_SCL, (kk > q) ? C_MSK : 0.f));
                    } else {
                        e = __builtin_amdgcn_exp2f(sacc[mt][nt][r] * C_SCL);
                    }
                    pk[r] = (f16)e;
                }
                *(f16x4*)&Ps[wq * 32 + nt * 16 + ln][mt * 16 + rg] = pk;
            }
        }

        // O += P.V ; rowsum += P.1  (Ps wave-private: intra-wave lgkm ordering suffices)
#pragma unroll
        for (int kk = 0; kk < 2; kk++) {
            f16x8 ap[2], bv[4];
#pragma unroll
            for (int mt = 0; mt < 2; mt++)
                ap[mt] = *(const f16x8*)&Ps[wq * 32 + mt * 16 + ln][kk * 32 + g8];
#pragma unroll
            for (int dt = 0; dt < 4; dt++)
                bv[dt] = *(const f16x8*)&Vs[dt * 16 + ln][kk * 32 + g8];
#pragma unroll
            for (int mt = 0; mt < 2; mt++) {
#pragma unroll
                for (int dt = 0; dt < 4; dt++)
                    oacc[mt][dt] = MFMA16(ap[mt], bv[dt], oacc[mt][dt]);
                osum[mt] = MFMA16(ap[mt], ones, osum[mt]);
            }
        }
    }

    // epilogue: osum C-layout row = 4g+r matches oacc rows exactly
#pragma unroll
    for (int mt = 0; mt < 2; mt++)
#pragma unroll
        for (int r = 0; r < 4; r++) {
            float inv = __builtin_amdgcn_rcpf(osum[mt][r]);
            int row = b * 2048 + q0 + wq * 32 + mt * 16 + rg + r;
#pragma unroll
            for (int dt = 0; dt < 4; dt++)
                Ob[(size_t)row * 1024 + h * 64 + dt * 16 + ln] =
                    (f16)(oacc[mt][dt][r] * inv);
        }
}

// ---------------- host launch ----------------
extern "C" void kernel_launch(void* const* d_in, const int* in_sizes, int n_in,
                              void* d_out, int out_size, void* d_ws, size_t ws_size,
                              hipStream_t stream) {
    const float* x = (const float*)d_in[0];
    const float* Wq = (const float*)d_in[1];
    const float* Wk = (const float*)d_in[2];
    const float* Wv = (const float*)d_in[3];
    const float* Wr = (const float*)d_in[4];
    float* out = (float*)d_out;

    f16* ws = (f16*)d_ws;
    f16* xb    = ws;                    // 8192*1024
    f16* Wqkvt = xb + 8388608;          // 3072*1024
    f16* Wrt   = Wqkvt + 3145728;       // 1024*1024
    f16* QKVb  = Wrt + 1048576;         // 8192*3072
    f16* Vtb   = QKVb + 25165824;       // 64bh * 64d * 2048s
    f16* Obuf  = Vtb + 8388608;         // 8192*1024

    k_convert<<<8192, 256, 0, stream>>>(x, xb, 8388608);
    dim3 tb(32, 8);
    k_transpose_w4<<<dim3(32, 32, 4), tb, 0, stream>>>(Wq, Wk, Wv, Wr, Wqkvt, Wrt);
    k_gemm_bt<true><<<dim3(24, 64), 256, 0, stream>>>(xb, Wqkvt, QKVb, 8192, 3072, 1024);
    k_transpose_v<<<dim3(64, 2, 64), tb, 0, stream>>>(QKVb, Vtb);
    k_attn<<<dim3(64, 16), 256, 0, stream>>>(QKVb, Vtb, Obuf);
    k_gemm_bt<false><<<dim3(8, 64), 256, 0, stream>>>(Obuf, Wrt, out, 8192, 1024, 1024);
}

// Round 5
// 290.579 us; speedup vs baseline: 1.0135x; 1.0135x over previous
//
#include <hip/hip_runtime.h>

typedef _Float16 f16;
typedef _Float16 f16x8 __attribute__((ext_vector_type(8)));
typedef _Float16 f16x4 __attribute__((ext_vector_type(4)));
typedef float f32x4 __attribute__((ext_vector_type(4)));
typedef float f32x16 __attribute__((ext_vector_type(16)));

#define MFMA16(A, B, C) __builtin_amdgcn_mfma_f32_16x16x32_f16((A), (B), (C), 0, 0, 0)
#define MFMA32(A, B, C) __builtin_amdgcn_mfma_f32_32x32x16_f16((A), (B), (C), 0, 0, 0)
// legacy K=16 shape: A/B are f16x4; A-layout = lane holds row m=l&15, k=(l>>4)*4+j --
// exactly the C/D layout of our S^T accumulator, so P stays in registers.
#define MFMA16K16(A, B, C) __builtin_amdgcn_mfma_f32_16x16x16f16((A), (B), (C), 0, 0, 0)

// async global->LDS, 16B per lane, dest = wave-uniform base + lane*16
__device__ __forceinline__ void async16(void* lds, const void* gp) {
    __builtin_amdgcn_global_load_lds(
        (__attribute__((address_space(1))) void*)(gp),
        (__attribute__((address_space(3))) void*)(lds), 16, 0, 0);
}

// ---------------- fp32 -> fp16 cast (vectorized) ----------------
__global__ __launch_bounds__(256) void k_convert(const float* __restrict__ in,
                                                 f16* __restrict__ out, int n) {
    int i = (blockIdx.x * 256 + threadIdx.x) * 4;
    if (i + 3 < n) {
        float4 v = *(const float4*)(in + i);
        f16x4 o = {(f16)v.x, (f16)v.y, (f16)v.z, (f16)v.w};
        *(f16x4*)(out + i) = o;
    }
}

// ---------------- transpose + cast all four 1024x1024 weights in one launch ----------------
__global__ __launch_bounds__(256) void k_transpose_w4(const float* __restrict__ Wq,
                                                      const float* __restrict__ Wk,
                                                      const float* __restrict__ Wv,
                                                      const float* __restrict__ Wr,
                                                      f16* __restrict__ Wqkvt,
                                                      f16* __restrict__ Wrt) {
    __shared__ float tile[32][33];
    int z = blockIdx.z;
    const float* W = (z == 0) ? Wq : (z == 1) ? Wk : (z == 2) ? Wv : Wr;
    f16* Wt = (z == 3) ? Wrt : Wqkvt + z * 1048576;
    int c0 = blockIdx.x * 32, r0 = blockIdx.y * 32;
    int tx = threadIdx.x, ty = threadIdx.y;  // 32 x 8
#pragma unroll
    for (int j = 0; j < 32; j += 8)
        tile[ty + j][tx] = W[(r0 + ty + j) * 1024 + c0 + tx];
    __syncthreads();
#pragma unroll
    for (int j = 0; j < 32; j += 8)
        Wt[(c0 + ty + j) * 1024 + r0 + tx] = (f16)tile[tx][ty + j];
}

// ---------------- transpose V slice of QKV into Vt[bh][d][s] ----------------
__global__ __launch_bounds__(256) void k_transpose_v(const f16* __restrict__ QKV,
                                                     f16* __restrict__ Vt) {
    __shared__ f16 tile[32][33];
    int s0 = blockIdx.x * 32;
    int d0 = blockIdx.y * 32;
    int bh = blockIdx.z;
    int b = bh >> 4, h = bh & 15;
    int tx = threadIdx.x, ty = threadIdx.y;  // 32 x 8
#pragma unroll
    for (int j = 0; j < 32; j += 8)
        tile[ty + j][tx] = QKV[(b * 2048 + s0 + ty + j) * 3072 + 2048 + h * 64 + d0 + tx];
    __syncthreads();
#pragma unroll
    for (int j = 0; j < 32; j += 8)
        Vt[(bh * 64 + d0 + ty + j) * 2048 + s0 + tx] = tile[tx][ty + j];
}

// ---------------- GEMM: C[M][N] = A[M][K] * Bt[N][K]^T, 32x32x16 MFMA ----------------
template <bool OUT_F16>
__global__ __launch_bounds__(256, 4) void k_gemm_bt(const f16* __restrict__ A,
                                                    const f16* __restrict__ Bt,
                                                    void* __restrict__ Cv,
                                                    int M, int N, int K) {
    __shared__ f16 As[128][32];
    __shared__ f16 Bs[128][32];
    int t = threadIdx.x;
    int lane = t & 63, w = t >> 6;
    int wm = (w >> 1) * 64, wn = (w & 1) * 64;
    int m0 = blockIdx.y * 128, n0 = blockIdx.x * 128;
    int ln = lane & 31, kh = lane >> 5;
    int sw = (ln >> 1) & 3;

    int lin0 = w * 128 + lane, lin1 = lin0 + 64;
    int r0 = lin0 >> 2, c0 = (lin0 & 3) ^ ((r0 >> 1) & 3);
    int r1 = lin1 >> 2, c1 = (lin1 & 3) ^ ((r1 >> 1) & 3);
    const f16* gA0 = A + (size_t)(m0 + r0) * K + c0 * 8;
    const f16* gA1 = A + (size_t)(m0 + r1) * K + c1 * 8;
    const f16* gB0 = Bt + (size_t)(n0 + r0) * K + c0 * 8;
    const f16* gB1 = Bt + (size_t)(n0 + r1) * K + c1 * 8;
    f16* lA0 = &As[0][0] + w * 1024;
    f16* lB0 = &Bs[0][0] + w * 1024;

    f32x16 acc[2][2] = {};

    for (int k0 = 0; k0 < K; k0 += 32) {
        __syncthreads();
        async16(lA0, gA0 + k0);
        async16(lA0 + 512, gA1 + k0);
        async16(lB0, gB0 + k0);
        async16(lB0 + 512, gB1 + k0);
        __syncthreads();
#pragma unroll
        for (int kd = 0; kd < 2; kd++) {
            int c = kd * 2 + kh;
            f16x8 af[2], bf[2];
#pragma unroll
            for (int mt = 0; mt < 2; mt++)
                af[mt] = *(const f16x8*)&As[wm + mt * 32 + ln][(c ^ sw) * 8];
#pragma unroll
            for (int nt = 0; nt < 2; nt++)
                bf[nt] = *(const f16x8*)&Bs[wn + nt * 32 + ln][(c ^ sw) * 8];
#pragma unroll
            for (int mt = 0; mt < 2; mt++)
#pragma unroll
                for (int nt = 0; nt < 2; nt++)
                    acc[mt][nt] = MFMA32(af[mt], bf[nt], acc[mt][nt]);
        }
    }

#pragma unroll
    for (int mt = 0; mt < 2; mt++)
#pragma unroll
        for (int nt = 0; nt < 2; nt++)
#pragma unroll
            for (int r = 0; r < 16; r++) {
                int row = m0 + wm + mt * 32 + (r & 3) + 8 * (r >> 2) + 4 * kh;
                int col = n0 + wn + nt * 32 + ln;
                float v = acc[mt][nt][r];
                if (OUT_F16)
                    ((f16*)Cv)[(size_t)row * N + col] = (f16)v;
                else
                    ((float*)Cv)[(size_t)row * N + col] = v;
            }
}

// ---------------- flash attention v5 ----------------
// q-tile 256 (4 waves x 64 q rows). grid (64 bh, 8) with qt remap pairing heavy+light
// per CU. S^T=K.Q^T via 16x16x32; P stays in REGISTERS (S^T C-layout == A-layout of
// 16x16x16 MFMA); PV + row-sum ones-trick via 16x16x16. LDS = K,V tiles only (18.4KB).
__global__ __launch_bounds__(256, 2) void k_attn(const f16* __restrict__ QKV,
                                                 const f16* __restrict__ Vt,
                                                 f16* __restrict__ Ob) {
    __shared__ f16 Ks[64][72];
    __shared__ f16 Vs[64][72];  // V^T tile: [d][k]
    int bh = blockIdx.x;
    int y = blockIdx.y;
    int qt = (y < 4) ? (7 - y) : (y - 4);  // CU gets (32+4)/(28+8)/(24+12)/(20+16) tiles
    int b = bh >> 4, h = bh & 15;
    int q0 = qt * 256;
    int t = threadIdx.x, lane = t & 63, wq = t >> 6;
    int ln = lane & 15, g = lane >> 4, g8 = g * 8, rg = g * 4;
    int qw = q0 + wq * 64;  // this wave's q base (64 rows)

    // staging coords: K tile 8KB = 512 x 16B chunks; 256 threads x 2 (same for V)
    int kr0 = t >> 3, kc0 = (t & 7) * 8;
    int kr1 = (t + 256) >> 3, kc1 = (t & 7) * 8;  // rows 32..63
    const f16* Kbase = QKV + (size_t)b * 2048 * 3072 + 1024 + h * 64;
    const f16* Vbase = Vt + (size_t)bh * 64 * 2048;

    const float C_SCL = 0.18033688f;  // 0.125 * log2(e)
    const float C_MSK = -72.134752f;  // -50 * log2(e)
    f16x4 ones4 = {(f16)1.f, (f16)1.f, (f16)1.f, (f16)1.f};

    // Q fragments (B-operand of S^T): 4 x 16 q rows, 2 k-halves of d
    f16x8 bq[4][2];
#pragma unroll
    for (int nt = 0; nt < 4; nt++)
#pragma unroll
        for (int kd = 0; kd < 2; kd++)
            bq[nt][kd] = *(const f16x8*)(QKV +
                (size_t)(b * 2048 + qw + nt * 16 + ln) * 3072 + h * 64 + kd * 32 + g8);

    // initial prefetch: tile 0 (nk >= 4 always)
    int4 rk0 = *(const int4*)(Kbase + (size_t)kr0 * 3072 + kc0);
    int4 rk1 = *(const int4*)(Kbase + (size_t)kr1 * 3072 + kc1);
    int4 rv0 = *(const int4*)(Vbase + (size_t)kr0 * 2048 + kc0);
    int4 rv1 = *(const int4*)(Vbase + (size_t)kr1 * 2048 + kc1);

    f32x4 oacc[4][4] = {};  // [nt: q16][dt: d16]
    f32x4 osum[4] = {};
    int nk = 4 * qt + 4;

    for (int kt = 0; kt < nk; kt++) {
        int k0 = kt * 64;
        __syncthreads();
        *(int4*)&Ks[kr0][kc0] = rk0;
        *(int4*)&Ks[kr1][kc1] = rk1;
        *(int4*)&Vs[kr0][kc0] = rv0;
        *(int4*)&Vs[kr1][kc1] = rv1;
        if (kt + 1 < nk) {
            int kn = k0 + 64;
            rk0 = *(const int4*)(Kbase + (size_t)(kn + kr0) * 3072 + kc0);
            rk1 = *(const int4*)(Kbase + (size_t)(kn + kr1) * 3072 + kc1);
            rv0 = *(const int4*)(Vbase + (size_t)kr0 * 2048 + kn + kc0);
            rv1 = *(const int4*)(Vbase + (size_t)kr1 * 2048 + kn + kc1);
        }
        __syncthreads();

        // tile fully above this wave's diagonal -> ~e^-50 ~ 0 contribution
        if (k0 > qw + 63) continue;  // wave-uniform; barriers stay outside

        // S^T tile: D[m=k 64][n=q 64]
        f32x4 sacc[4][4] = {};
#pragma unroll
        for (int kd = 0; kd < 2; kd++) {
            f16x8 ak[4];
#pragma unroll
            for (int mt = 0; mt < 4; mt++)
                ak[mt] = *(const f16x8*)&Ks[mt * 16 + ln][kd * 32 + g8];
#pragma unroll
            for (int mt = 0; mt < 4; mt++)
#pragma unroll
                for (int nt = 0; nt < 4; nt++)
                    sacc[mt][nt] = MFMA16(ak[mt], bq[nt][kd], sacc[mt][nt]);
        }

        // softmax numerator (fixed max 0) -> P in registers, fp16
        bool needs_mask = (k0 + 63 > qw);
        f16x4 pk[4][4];
#pragma unroll
        for (int nt = 0; nt < 4; nt++) {
            int q = qw + nt * 16 + ln;
#pragma unroll
            for (int mt = 0; mt < 4; mt++) {
#pragma unroll
                for (int r = 0; r < 4; r++) {
                    float e;
                    if (needs_mask) {
                        int kk = k0 + mt * 16 + rg + r;
                        e = __builtin_amdgcn_exp2f(
                            fmaf(sacc[mt][nt][r], C_SCL, (kk > q) ? C_MSK : 0.f));
                    } else {
                        e = __builtin_amdgcn_exp2f(sacc[mt][nt][r] * C_SCL);
                    }
                    pk[mt][nt][r] = (f16)e;
                }
            }
        }

        // O += P.V and rowsum += P.1 via 16x16x16 (A = pk registers, B = V^T f16x4)
#pragma unroll
        for (int mt = 0; mt < 4; mt++) {
            f16x4 bv[4];
#pragma unroll
            for (int dt = 0; dt < 4; dt++)
                bv[dt] = *(const f16x4*)&Vs[dt * 16 + ln][mt * 16 + rg];
#pragma unroll
            for (int nt = 0; nt < 4; nt++) {
#pragma unroll
                for (int dt = 0; dt < 4; dt++)
                    oacc[nt][dt] = MFMA16K16(pk[mt][nt], bv[dt], oacc[nt][dt]);
                osum[nt] = MFMA16K16(pk[mt][nt], ones4, osum[nt]);
            }
        }
    }

    // epilogue: osum rows (rg+r) match oacc rows exactly
#pragma unroll
    for (int nt = 0; nt < 4; nt++)
#pragma unroll
        for (int r = 0; r < 4; r++) {
            float inv = __builtin_amdgcn_rcpf(osum[nt][r]);
            int row = b * 2048 + qw + nt * 16 + rg + r;
#pragma unroll
            for (int dt = 0; dt < 4; dt++)
                Ob[(size_t)row * 1024 + h * 64 + dt * 16 + ln] =
                    (f16)(oacc[nt][dt][r] * inv);
        }
}

// ---------------- host launch ----------------
extern "C" void kernel_launch(void* const* d_in, const int* in_sizes, int n_in,
                              void* d_out, int out_size, void* d_ws, size_t ws_size,
                              hipStream_t stream) {
    const float* x = (const float*)d_in[0];
    const float* Wq = (const float*)d_in[1];
    const float* Wk = (const float*)d_in[2];
    const float* Wv = (const float*)d_in[3];
    const float* Wr = (const float*)d_in[4];
    float* out = (float*)d_out;

    f16* ws = (f16*)d_ws;
    f16* xb    = ws;                    // 8192*1024
    f16* Wqkvt = xb + 8388608;          // 3072*1024
    f16* Wrt   = Wqkvt + 3145728;       // 1024*1024
    f16* QKVb  = Wrt + 1048576;         // 8192*3072
    f16* Vtb   = QKVb + 25165824;       // 64bh * 64d * 2048s
    f16* Obuf  = Vtb + 8388608;         // 8192*1024

    k_convert<<<8192, 256, 0, stream>>>(x, xb, 8388608);
    dim3 tb(32, 8);
    k_transpose_w4<<<dim3(32, 32, 4), tb, 0, stream>>>(Wq, Wk, Wv, Wr, Wqkvt, Wrt);
    k_gemm_bt<true><<<dim3(24, 64), 256, 0, stream>>>(xb, Wqkvt, QKVb, 8192, 3072, 1024);
    k_transpose_v<<<dim3(64, 2, 64), tb, 0, stream>>>(QKVb, Vtb);
    k_attn<<<dim3(64, 8), 256, 0, stream>>>(QKVb, Vtb, Obuf);
    k_gemm_bt<false><<<dim3(8, 64), 256, 0, stream>>>(Obuf, Wrt, out, 8192, 1024, 1024);
}